// Round 11
// baseline (114.129 us; speedup 1.0000x reference)
//
#include <hip/hip_runtime.h>
#include <hip/hip_bf16.h>
#include <hip/hip_fp16.h>
#include <math.h>

// Problem constants: B=16, L=96, H=128.
#define BB 16
#define LL 96
#define HH 128

typedef __attribute__((ext_vector_type(8))) short short8;
typedef __attribute__((ext_vector_type(4))) float f32x4;

// Only slice kh=63 of attn_conv_w matters (input height 1, SAME pad (63,64)).
// Only slice kw=63 of cvg_conv_w matters (input width 1, SAME pad (63,64)).
//
// ws layout (float-unit offsets):
#define WS_W    0              // bf16 W [i][o][e ^ ((o&7)<<3)] : 1,179,648 shorts
#define WS_E    589824         // dual-copy bf16 enc rows [b][i][272 u32] : 417,792 u32
#define WS_DEC  1007616        // 16*128 fp32
#define WS_CVG  1009664        // 16*96  fp32
#define WS_SC   1011200        // 16*96  fp32 (score scratch, atomic)
#define WS_CNT  1012736        // 16 ints (per-b completion counters)
#define WS_P    1012752        // fp16 partials [kc][b][o][w]: 32*16*96*128 halves

// ---------------- P: W->bf16 swizzled, dual-copy E rows, dec_f/cvg_f, zero counters --------
__global__ __launch_bounds__(256) void prep_kernel(
        const float* __restrict__ hidden,
        const float* __restrict__ enc,
        const float* __restrict__ coverage,
        const float* __restrict__ attn_w,
        const float* __restrict__ cvg_w,
        const float* __restrict__ cvg_b,
        const float* __restrict__ dec_w,
        const float* __restrict__ dec_b,
        float* __restrict__ ws) {
    const int bid = blockIdx.x;
    const int tid = threadIdx.x;
    if (bid < 96) {
        // W slice: ws_W[i][o][e] = bf16(attn_w[o][i][63][ e ^ ((o&7)<<3) ])   (round-8 verbatim)
        const int i = bid;
        unsigned short* wout = (unsigned short*)(ws + WS_W);
        for (int idx = tid; idx < LL * HH; idx += 256) {
            const int o = idx >> 7, e = idx & 127;
            const int esrc = e ^ ((o & 7) << 3);
            float v = attn_w[(((size_t)o * LL + i) * HH + 63) * HH + esrc];
            __hip_bfloat16 h = __float2bfloat16(v);
            wout[(size_t)i * LL * HH + idx] = *(unsigned short*)&h;
        }
    } else if (bid < 112) {
        // dual-copy bf16 padded enc rows, per row 272 u32:
        //  [0..127]   w0[q] = (e(2q),   e(2q+1))
        //  [129..256] w1[q] = (e(2q+1), e(2q+2));  e(t)=enc[t-63] for t in [63,191) else 0
        const int b = bid - 96;
        unsigned int* eout = (unsigned int*)(ws + WS_E) + (size_t)b * LL * 272;
        const float* esrc = enc + (size_t)b * LL * HH;
        for (int idx = tid; idx < LL * 272; idx += 256) {
            const int i = idx / 272, c = idx % 272;
            int t0 = -1, t1 = -1;
            if (c < 128) { t0 = 2 * c; t1 = 2 * c + 1; }
            else if (c >= 129 && c < 257) { int q = c - 129; t0 = 2 * q + 1; t1 = 2 * q + 2; }
            unsigned int lo16 = 0, hi16 = 0;
            if (t0 >= 63 && t0 < 191) {
                __hip_bfloat16 h = __float2bfloat16(esrc[i * HH + t0 - 63]);
                lo16 = *(unsigned short*)&h;
            }
            if (t1 >= 63 && t1 < 191) {
                __hip_bfloat16 h = __float2bfloat16(esrc[i * HH + t1 - 63]);
                hi16 = *(unsigned short*)&h;
            }
            eout[idx] = lo16 | (hi16 << 16);
        }
    } else {
        const int b = bid - 112;
        if (tid == 0)
            __hip_atomic_store((int*)(ws + WS_CNT) + b, 0,
                               __ATOMIC_RELAXED, __HIP_MEMORY_SCOPE_AGENT);
        __shared__ float hid[HH];
        __shared__ float cov[LL];
        if (tid < HH) hid[tid] = hidden[b * HH + tid];
        if (tid < LL) cov[tid] = coverage[b * LL + tid];
        __syncthreads();
        if (tid < HH) {
            float acc = dec_b[tid];
            for (int k = 0; k < HH; ++k) acc += hid[k] * dec_w[tid * HH + k];
            ws[WS_DEC + b * HH + tid] = acc;
        } else if (tid < HH + LL) {
            const int t = tid - HH;
            float a2 = cvg_b[t];
            for (int i2 = 0; i2 < LL; ++i2)
                a2 += cov[i2] * cvg_w[((size_t)t * LL + i2) * HH + 63];
            ws[WS_CVG + b * LL + t] = a2;
        }
    }
}

// ---------------- M: round-8 structure; B-path = dual-copy bf16 (no converts) -------------
// grid (kc=32, b=16); 256 threads = 4 w-split waves; 3 i-rows, K=384.
__global__ __launch_bounds__(256) void mfma_kernel(float* __restrict__ ws) {
    const int kc = blockIdx.x;   // 0..31
    const int b  = blockIdx.y;   // 0..15
    const int tid  = threadIdx.x;
    const int lane = tid & 63;
    const int wg   = tid >> 6;   // wave id 0..3 (w-split)
    const int lo   = lane & 15;
    const int hi   = lane >> 4;  // 0..3

    __shared__ __align__(16) short Abuf[LL * HH];        // 24KB bf16 W[o][e^]
    __shared__ __align__(16) unsigned int Ebuf[272];     // dual-copy bf16 row

    f32x4 acc[6][2];
#pragma unroll
    for (int a = 0; a < 6; ++a)
#pragma unroll
        for (int c = 0; c < 2; ++c) acc[a][c] = f32x4{0.f, 0.f, 0.f, 0.f};

    const short* wsrc = (const short*)(ws + WS_W);
    const unsigned int* esrc = (const unsigned int*)(ws + WS_E) + (size_t)b * LL * 272;
    // NOTE: no kc pre-offset; staging uses global row ig (round-7 bug avoided).

    for (int ii = 0; ii < 3; ++ii) {
        const int ig = kc * 3 + ii;   // global i row
        __syncthreads();
        {
            const short8* s8 = (const short8*)(wsrc + (size_t)ig * LL * HH);
            short8* d8 = (short8*)Abuf;
#pragma unroll
            for (int t = 0; t < 6; ++t) d8[tid + t * 256] = s8[tid + t * 256];
            if (tid < 68)
                *(uint4*)&Ebuf[tid * 4] = *(const uint4*)(esrc + (size_t)ig * 272 + tid * 4);
        }
        __syncthreads();

#pragma unroll
        for (int s = 0; s < 4; ++s) {      // k-step within i (m0 = 32s)
            short8 af[6];
#pragma unroll
            for (int ot = 0; ot < 6; ++ot) {
                const int o = ot * 16 + lo;
                const int idx8 = o * 16 + (((s << 2) + hi) ^ (o & 7));
                af[ot] = ((const short8*)Abuf)[idx8];
            }
#pragma unroll
            for (int wt = 0; wt < 2; ++wt) {
                const int t0 = s * 32 + hi * 8 + wg * 32 + wt * 16 + lo;  // <= 247
                const unsigned int* arr = Ebuf + ((lo & 1) ? 129 : 0) + (t0 >> 1);
                union { uint4 u; short8 s8; } bf;
                bf.u.x = arr[0]; bf.u.y = arr[1]; bf.u.z = arr[2]; bf.u.w = arr[3];
#pragma unroll
                for (int ot = 0; ot < 6; ++ot)
                    acc[ot][wt] = __builtin_amdgcn_mfma_f32_16x16x32_bf16(
                        af[ot], bf.s8, acc[ot][wt], 0, 0, 0);
            }
        }
    }

    // fp16 partial store, [kc][b][o][w], w lane-consecutive -> coalesced  (round-8 verbatim)
    __half* dst = (__half*)(ws + WS_P) + (size_t)(kc * BB + b) * LL * HH;
#pragma unroll
    for (int ot = 0; ot < 6; ++ot)
#pragma unroll
        for (int wt = 0; wt < 2; ++wt)
#pragma unroll
            for (int r = 0; r < 4; ++r) {
                const int o = ot * 16 + hi * 4 + r;     // C/D: row=(lane>>4)*4+reg
                const int w = wg * 32 + wt * 16 + lo;   //      col=lane&15
                dst[o * HH + w] = __float2half(acc[ot][wt][r]);
            }
}

// ---------------- RF: reduce -> scores; last block per b: softmax + outputs ----------------
__global__ __launch_bounds__(128) void reduceF_kernel(
        const float* __restrict__ attn_b,
        const float* __restrict__ vvec,
        const float* __restrict__ coverage,
        const float* __restrict__ enc,
        float* __restrict__ ws,
        float* __restrict__ out) {
    const int o = blockIdx.x;   // 0..95
    const int b = blockIdx.y;   // 0..15
    const int h = threadIdx.x;  // 0..127
    const __half* p = (const __half*)(ws + WS_P) + ((size_t)b * LL + o) * HH + h;
    float* sc_ws = ws + WS_SC;
    int* cnt = (int*)(ws + WS_CNT);

    float sum = 0.f;
#pragma unroll
    for (int kc = 0; kc < 32; ++kc)
        sum += __half2float(p[(size_t)kc * BB * LL * HH]);
    float ef = sum + attn_b[o] + ws[WS_DEC + b * HH + h] + ws[WS_CVG + b * LL + o];
    float s = tanhf(ef) * vvec[b * HH + h];
#pragma unroll
    for (int off = 32; off > 0; off >>= 1) s += __shfl_down(s, off, 64);

    __shared__ float r2[2];
    __shared__ int isLast;
    if ((h & 63) == 0) r2[h >> 6] = s;
    __syncthreads();
    if (h == 0) {
        float sc = r2[0] + r2[1];
        __hip_atomic_store(&sc_ws[b * LL + o], sc,
                           __ATOMIC_RELEASE, __HIP_MEMORY_SCOPE_AGENT);
        int old = __hip_atomic_fetch_add(&cnt[b], 1,
                                         __ATOMIC_ACQ_REL, __HIP_MEMORY_SCOPE_AGENT);
        isLast = (old == LL - 1);
    }
    __syncthreads();
    if (!isLast) return;

    // tail (validated round-5 structure): softmax + all three outputs for batch b
    __shared__ float scl[LL], atl[LL];
    if (h < LL)
        scl[h] = __hip_atomic_load(&sc_ws[b * LL + h],
                                   __ATOMIC_ACQUIRE, __HIP_MEMORY_SCOPE_AGENT);
    __syncthreads();
    float mx = -1e30f;
    for (int l = 0; l < LL; ++l) mx = fmaxf(mx, scl[l]);
    float den = 0.f;
    for (int l = 0; l < LL; ++l) den += expf(scl[l] - mx);
    if (h < LL) {
        float a = expf(scl[h] - mx) / den;
        atl[h] = a;
        out[BB * HH + b * LL + h] = a;                                   // attn
        out[BB * HH + BB * LL + b * LL + h] = coverage[b * LL + h] + a;  // new_coverage
    }
    __syncthreads();
    float c = 0.f;
#pragma unroll 8
    for (int l = 0; l < LL; ++l) c += atl[l] * enc[((size_t)b * LL + l) * HH + h];
    out[b * HH + h] = c;                                                 // context
}

extern "C" void kernel_launch(void* const* d_in, const int* in_sizes, int n_in,
                              void* d_out, int out_size, void* d_ws, size_t ws_size,
                              hipStream_t stream) {
    const float* hidden   = (const float*)d_in[0];
    const float* enc      = (const float*)d_in[1];
    const float* coverage = (const float*)d_in[2];
    const float* attn_w   = (const float*)d_in[3];
    const float* attn_b   = (const float*)d_in[4];
    const float* cvg_w    = (const float*)d_in[5];
    const float* cvg_b    = (const float*)d_in[6];
    const float* dec_w    = (const float*)d_in[7];
    const float* dec_b    = (const float*)d_in[8];
    const float* vvec     = (const float*)d_in[9];
    float* out = (float*)d_out;
    float* ws  = (float*)d_ws;

    prep_kernel<<<128, 256, 0, stream>>>(hidden, enc, coverage, attn_w,
                                         cvg_w, cvg_b, dec_w, dec_b, ws);
    mfma_kernel<<<dim3(32, BB), 256, 0, stream>>>(ws);
    reduceF_kernel<<<dim3(LL, BB), 128, 0, stream>>>(attn_b, vvec, coverage,
                                                     enc, ws, out);
}

// Round 12
// 58.865 us; speedup vs baseline: 1.9388x; 1.9388x over previous
//
#include <hip/hip_runtime.h>
#include <hip/hip_bf16.h>
#include <hip/hip_fp16.h>
#include <math.h>

// Problem constants: B=16, L=96, H=128.
#define BB 16
#define LL 96
#define HH 128

typedef __attribute__((ext_vector_type(8))) short short8;
typedef __attribute__((ext_vector_type(4))) float f32x4;

// Only slice kh=63 of attn_conv_w matters (input height 1, SAME pad (63,64)).
// Only slice kw=63 of cvg_conv_w matters (input width 1, SAME pad (63,64)).
//
// ws layout (float-unit offsets):
#define WS_W    0              // bf16 W [i][o][e ^ ((o&7)<<3)] : 1,179,648 shorts
#define WS_E    589824         // dual-copy bf16 enc rows [b][i][272 u32] : 417,792 u32
#define WS_DEC  1007616        // 16*128 fp32
#define WS_CVG  1009664        // 16*96  fp32
#define WS_SC   1011200        // 16*96  fp32
#define WS_P    1012736        // fp16 partials [kc][b][o][w]: 32*16*96*128 halves

// ---------------- P: W->bf16 swizzled, dual-copy E rows, dec_f, cvg_f ----------------
__global__ __launch_bounds__(256) void prep_kernel(
        const float* __restrict__ hidden,
        const float* __restrict__ enc,
        const float* __restrict__ coverage,
        const float* __restrict__ attn_w,
        const float* __restrict__ cvg_w,
        const float* __restrict__ cvg_b,
        const float* __restrict__ dec_w,
        const float* __restrict__ dec_b,
        float* __restrict__ ws) {
    const int bid = blockIdx.x;
    const int tid = threadIdx.x;
    if (bid < 96) {
        // W slice: ws_W[i][o][e] = bf16(attn_w[o][i][63][ e ^ ((o&7)<<3) ])   (round-8 verbatim)
        const int i = bid;
        unsigned short* wout = (unsigned short*)(ws + WS_W);
        for (int idx = tid; idx < LL * HH; idx += 256) {
            const int o = idx >> 7, e = idx & 127;
            const int esrc = e ^ ((o & 7) << 3);
            float v = attn_w[(((size_t)o * LL + i) * HH + 63) * HH + esrc];
            __hip_bfloat16 h = __float2bfloat16(v);
            wout[(size_t)i * LL * HH + idx] = *(unsigned short*)&h;
        }
    } else if (bid < 112) {
        // dual-copy bf16 padded enc rows, per row 272 u32 (validated r11, absmax unchanged):
        //  [0..127]   w0[q] = (e(2q),   e(2q+1))
        //  [129..256] w1[q] = (e(2q+1), e(2q+2));  e(t)=enc[t-63] for t in [63,191) else 0
        const int b = bid - 96;
        unsigned int* eout = (unsigned int*)(ws + WS_E) + (size_t)b * LL * 272;
        const float* esrc = enc + (size_t)b * LL * HH;
        for (int idx = tid; idx < LL * 272; idx += 256) {
            const int i = idx / 272, c = idx % 272;
            int t0 = -1, t1 = -1;
            if (c < 128) { t0 = 2 * c; t1 = 2 * c + 1; }
            else if (c >= 129 && c < 257) { int q = c - 129; t0 = 2 * q + 1; t1 = 2 * q + 2; }
            unsigned int lo16 = 0, hi16 = 0;
            if (t0 >= 63 && t0 < 191) {
                __hip_bfloat16 h = __float2bfloat16(esrc[i * HH + t0 - 63]);
                lo16 = *(unsigned short*)&h;
            }
            if (t1 >= 63 && t1 < 191) {
                __hip_bfloat16 h = __float2bfloat16(esrc[i * HH + t1 - 63]);
                hi16 = *(unsigned short*)&h;
            }
            eout[idx] = lo16 | (hi16 << 16);
        }
    } else {
        const int b = bid - 112;
        __shared__ float hid[HH];
        __shared__ float cov[LL];
        if (tid < HH) hid[tid] = hidden[b * HH + tid];
        if (tid < LL) cov[tid] = coverage[b * LL + tid];
        __syncthreads();
        if (tid < HH) {
            float acc = dec_b[tid];
            for (int k = 0; k < HH; ++k) acc += hid[k] * dec_w[tid * HH + k];
            ws[WS_DEC + b * HH + tid] = acc;
        } else if (tid < HH + LL) {
            const int t = tid - HH;
            float a2 = cvg_b[t];
            for (int i2 = 0; i2 < LL; ++i2)
                a2 += cov[i2] * cvg_w[((size_t)t * LL + i2) * HH + 63];
            ws[WS_CVG + b * LL + t] = a2;
        }
    }
}

// ---------------- M: round-8 structure; B-path = dual-copy bf16 (no converts) -------------
// grid (kc=32, b=16); 256 threads = 4 w-split waves; 3 i-rows, K=384.
__global__ __launch_bounds__(256) void mfma_kernel(float* __restrict__ ws) {
    const int kc = blockIdx.x;   // 0..31
    const int b  = blockIdx.y;   // 0..15
    const int tid  = threadIdx.x;
    const int lane = tid & 63;
    const int wg   = tid >> 6;   // wave id 0..3 (w-split)
    const int lo   = lane & 15;
    const int hi   = lane >> 4;  // 0..3

    __shared__ __align__(16) short Abuf[LL * HH];        // 24KB bf16 W[o][e^]
    __shared__ __align__(16) unsigned int Ebuf[272];     // dual-copy bf16 row

    f32x4 acc[6][2];
#pragma unroll
    for (int a = 0; a < 6; ++a)
#pragma unroll
        for (int c = 0; c < 2; ++c) acc[a][c] = f32x4{0.f, 0.f, 0.f, 0.f};

    const short* wsrc = (const short*)(ws + WS_W);
    const unsigned int* esrc = (const unsigned int*)(ws + WS_E) + (size_t)b * LL * 272;
    // NOTE: no kc pre-offset; staging uses global row ig.

    for (int ii = 0; ii < 3; ++ii) {
        const int ig = kc * 3 + ii;   // global i row
        __syncthreads();
        {
            const short8* s8 = (const short8*)(wsrc + (size_t)ig * LL * HH);
            short8* d8 = (short8*)Abuf;
#pragma unroll
            for (int t = 0; t < 6; ++t) d8[tid + t * 256] = s8[tid + t * 256];
            if (tid < 68)
                *(uint4*)&Ebuf[tid * 4] = *(const uint4*)(esrc + (size_t)ig * 272 + tid * 4);
        }
        __syncthreads();

#pragma unroll
        for (int s = 0; s < 4; ++s) {      // k-step within i (m0 = 32s)
            short8 af[6];
#pragma unroll
            for (int ot = 0; ot < 6; ++ot) {
                const int o = ot * 16 + lo;
                const int idx8 = o * 16 + (((s << 2) + hi) ^ (o & 7));
                af[ot] = ((const short8*)Abuf)[idx8];
            }
#pragma unroll
            for (int wt = 0; wt < 2; ++wt) {
                const int t0 = s * 32 + hi * 8 + wg * 32 + wt * 16 + lo;  // <= 247
                const unsigned int* arr = Ebuf + ((lo & 1) ? 129 : 0) + (t0 >> 1);
                union { uint4 u; short8 s8; } bf;
                bf.u.x = arr[0]; bf.u.y = arr[1]; bf.u.z = arr[2]; bf.u.w = arr[3];
#pragma unroll
                for (int ot = 0; ot < 6; ++ot)
                    acc[ot][wt] = __builtin_amdgcn_mfma_f32_16x16x32_bf16(
                        af[ot], bf.s8, acc[ot][wt], 0, 0, 0);
            }
        }
    }

    // fp16 partial store, [kc][b][o][w], w lane-consecutive -> coalesced  (round-8 verbatim)
    __half* dst = (__half*)(ws + WS_P) + (size_t)(kc * BB + b) * LL * HH;
#pragma unroll
    for (int ot = 0; ot < 6; ++ot)
#pragma unroll
        for (int wt = 0; wt < 2; ++wt)
#pragma unroll
            for (int r = 0; r < 4; ++r) {
                const int o = ot * 16 + hi * 4 + r;     // C/D: row=(lane>>4)*4+reg
                const int w = wg * 32 + wt * 16 + lo;   //      col=lane&15
                dst[o * HH + w] = __float2half(acc[ot][wt][r]);
            }
}

// ---------------- R: sum partials + bias/dec/cvg -> tanh -> dot v -> scores (round-8) -----
__global__ __launch_bounds__(128) void reduce_kernel(
        const float* __restrict__ attn_b,
        const float* __restrict__ vvec,
        float* __restrict__ ws) {
    const int o = blockIdx.x;   // 0..95
    const int b = blockIdx.y;   // 0..15
    const int h = threadIdx.x;  // 0..127
    const __half* p = (const __half*)(ws + WS_P) + ((size_t)b * LL + o) * HH + h;
    float sum = 0.f;
#pragma unroll
    for (int kc = 0; kc < 32; ++kc)
        sum += __half2float(p[(size_t)kc * BB * LL * HH]);
    float ef = sum + attn_b[o] + ws[WS_DEC + b * HH + h] + ws[WS_CVG + b * LL + o];
    float s = tanhf(ef) * vvec[b * HH + h];
#pragma unroll
    for (int off = 32; off > 0; off >>= 1) s += __shfl_down(s, off, 64);
    __shared__ float r2[2];
    if ((h & 63) == 0) r2[h >> 6] = s;
    __syncthreads();
    if (h == 0) ws[WS_SC + b * LL + o] = r2[0] + r2[1];
}

// ---------------- F: softmax + outputs (round-8 verbatim) ----------------
__global__ void finalize_kernel(const float* __restrict__ ws_scores,
                                const float* __restrict__ coverage,
                                const float* __restrict__ enc,
                                float* __restrict__ out) {
    int b = blockIdx.x;
    int t = threadIdx.x;  // 0..127
    __shared__ float sc[LL];
    __shared__ float at[LL];
    if (t < LL) sc[t] = ws_scores[b * LL + t];
    __syncthreads();

    float mx = -1e30f;
    for (int l = 0; l < LL; ++l) mx = fmaxf(mx, sc[l]);
    float sum = 0.f;
    for (int l = 0; l < LL; ++l) sum += expf(sc[l] - mx);

    if (t < LL) {
        float a = expf(sc[t] - mx) / sum;
        at[t] = a;
        out[BB * HH + b * LL + t] = a;                                   // attn
        out[BB * HH + BB * LL + b * LL + t] = coverage[b * LL + t] + a;  // new_coverage
    }
    __syncthreads();

    float ctx = 0.f;
#pragma unroll 8
    for (int l = 0; l < LL; ++l) ctx += at[l] * enc[((size_t)b * LL + l) * HH + t];
    out[b * HH + t] = ctx;                                               // context
}

extern "C" void kernel_launch(void* const* d_in, const int* in_sizes, int n_in,
                              void* d_out, int out_size, void* d_ws, size_t ws_size,
                              hipStream_t stream) {
    const float* hidden   = (const float*)d_in[0];
    const float* enc      = (const float*)d_in[1];
    const float* coverage = (const float*)d_in[2];
    const float* attn_w   = (const float*)d_in[3];
    const float* attn_b   = (const float*)d_in[4];
    const float* cvg_w    = (const float*)d_in[5];
    const float* cvg_b    = (const float*)d_in[6];
    const float* dec_w    = (const float*)d_in[7];
    const float* dec_b    = (const float*)d_in[8];
    const float* vvec     = (const float*)d_in[9];
    float* out = (float*)d_out;
    float* ws  = (float*)d_ws;

    prep_kernel<<<128, 256, 0, stream>>>(hidden, enc, coverage, attn_w,
                                         cvg_w, cvg_b, dec_w, dec_b, ws);
    mfma_kernel<<<dim3(32, BB), 256, 0, stream>>>(ws);
    reduce_kernel<<<dim3(LL, BB), 128, 0, stream>>>(attn_b, vvec, ws);
    finalize_kernel<<<BB, HH, 0, stream>>>(ws + WS_SC, coverage, enc, out);
}

// Round 13
// 42.166 us; speedup vs baseline: 2.7066x; 1.3960x over previous
//
#include <hip/hip_runtime.h>
#include <hip/hip_bf16.h>
#include <hip/hip_fp16.h>
#include <math.h>

// Problem constants: B=16, L=96, H=128.
#define BB 16
#define LL 96
#define HH 128

typedef __attribute__((ext_vector_type(8))) short short8;
typedef __attribute__((ext_vector_type(4))) float f32x4;

// Only slice kh=63 of attn_conv_w matters (input height 1, SAME pad (63,64)).
// Only slice kw=63 of cvg_conv_w matters (input width 1, SAME pad (63,64)).
//
// ws layout (float units) — round-8 layout, unchanged:
#define WS_W    0              // bf16 W [i][o][e ^ ((o&7)<<3)], 1179648 shorts
#define WS_E    589824         // 16*96*256 fp32 zero-padded enc rows [b][i][256]
#define WS_DEC  983040         // 16*128
#define WS_CVG  985088         // 16*96
#define WS_SC   986624         // 16*96
#define WS_P    988160         // fp16 partials [kc][b][o][w]: 32*16*96*128 halves

// ---------------- P1: convert W->bf16 (swizzled), build padded enc, dec_f, cvg_f ----------------
__global__ __launch_bounds__(256) void prep_kernel(
        const float* __restrict__ hidden,
        const float* __restrict__ enc,
        const float* __restrict__ coverage,
        const float* __restrict__ attn_w,
        const float* __restrict__ cvg_w,
        const float* __restrict__ cvg_b,
        const float* __restrict__ dec_w,
        const float* __restrict__ dec_b,
        float* __restrict__ ws) {
    const int bid = blockIdx.x;
    const int tid = threadIdx.x;
    if (bid < 96) {
        // W slice: ws_W[i][o][e] = bf16(attn_w[o][i][63][ e ^ ((o&7)<<3) ])
        const int i = bid;
        unsigned short* wout = (unsigned short*)(ws + WS_W);
        for (int idx = tid; idx < LL * HH; idx += 256) {
            const int o = idx >> 7, e = idx & 127;
            const int esrc = e ^ ((o & 7) << 3);
            float v = attn_w[(((size_t)o * LL + i) * HH + 63) * HH + esrc];
            __hip_bfloat16 h = __float2bfloat16(v);
            wout[(size_t)i * LL * HH + idx] = *(unsigned short*)&h;
        }
    } else if (bid < 112) {
        // padded enc rows: ws_E[b][i][t] = enc[b][i][t-63] for t in [63,191), else 0
        const int b = bid - 96;
        float* eout = ws + WS_E + (size_t)b * LL * 256;
        for (int idx = tid; idx < LL * 256; idx += 256) {
            const int i = idx >> 8, t = idx & 255;
            eout[idx] = (t >= 63 && t < 191) ? enc[((size_t)b * LL + i) * HH + (t - 63)] : 0.f;
        }
    } else {
        const int b = bid - 112;
        __shared__ float hid[HH];
        __shared__ float cov[LL];
        if (tid < HH) hid[tid] = hidden[b * HH + tid];
        if (tid < LL) cov[tid] = coverage[b * LL + tid];
        __syncthreads();
        if (tid < HH) {
            float acc = dec_b[tid];
            for (int k = 0; k < HH; ++k) acc += hid[k] * dec_w[tid * HH + k];
            ws[WS_DEC + b * HH + tid] = acc;
        } else if (tid < HH + LL) {
            const int t = tid - HH;
            float a2 = cvg_b[t];
            for (int i2 = 0; i2 < LL; ++i2)
                a2 += cov[i2] * cvg_w[((size_t)t * LL + i2) * HH + 63];
            ws[WS_CVG + b * LL + t] = a2;
        }
    }
}

// ---------------- M: round-8 compute body + T14 async-STAGE split, double-buffered ---------
// grid (kc=32, b=16); 256 threads = 4 w-split waves; 3 i-rows, K=384.
// Phase r: issue global loads for row r+1 (regs) -> compute row r -> ds_write row r+1 -> barrier.
__global__ __launch_bounds__(256) void mfma_kernel(float* __restrict__ ws) {
    const int kc = blockIdx.x;   // 0..31
    const int b  = blockIdx.y;   // 0..15
    const int tid  = threadIdx.x;
    const int lane = tid & 63;
    const int wg   = tid >> 6;   // wave id 0..3
    const int lo   = lane & 15;
    const int hi   = lane >> 4;  // 0..3

    __shared__ __align__(16) short Abuf[2][LL * HH];  // 2 x 24KB, bf16 W[o][e^]
    __shared__ __align__(16) float Ebuf[2][256];      // 2 x padded enc row (fp32)

    f32x4 acc[6][2];
#pragma unroll
    for (int a = 0; a < 6; ++a)
#pragma unroll
        for (int c = 0; c < 2; ++c) acc[a][c] = f32x4{0.f, 0.f, 0.f, 0.f};

    const short* wsrc = (const short*)(ws + WS_W);
    const float* esrc = ws + WS_E + (size_t)b * LL * 256;

    short8 sA[6];
    float4 sE;

    auto gload = [&](int r) {                 // global -> regs (issue early)
        const short8* s8 = (const short8*)(wsrc + (size_t)(kc * 3 + r) * LL * HH);
#pragma unroll
        for (int t = 0; t < 6; ++t) sA[t] = s8[tid + t * 256];
        if (tid < 64) sE = ((const float4*)(esrc + (kc * 3 + r) * 256))[tid];
    };
    auto lwrite = [&](int buf) {              // regs -> LDS (write late)
        short8* d8 = (short8*)Abuf[buf];
#pragma unroll
        for (int t = 0; t < 6; ++t) d8[tid + t * 256] = sA[t];
        if (tid < 64) ((float4*)Ebuf[buf])[tid] = sE;
    };
    auto compute = [&](int buf) {             // round-8 body verbatim, on buffer `buf`
#pragma unroll
        for (int s = 0; s < 4; ++s) {
            short8 af[6];
#pragma unroll
            for (int ot = 0; ot < 6; ++ot) {
                const int o = ot * 16 + lo;
                const int idx8 = o * 16 + (((s << 2) + hi) ^ (o & 7));
                af[ot] = ((const short8*)Abuf[buf])[idx8];
            }
#pragma unroll
            for (int wt = 0; wt < 2; ++wt) {
                const int t0 = s * 32 + hi * 8 + wg * 32 + wt * 16 + lo;  // <= 247
                union { short8 s8; __hip_bfloat16 h[8]; } bf;
#pragma unroll
                for (int j = 0; j < 8; ++j) bf.h[j] = __float2bfloat16(Ebuf[buf][t0 + j]);
#pragma unroll
                for (int ot = 0; ot < 6; ++ot)
                    acc[ot][wt] = __builtin_amdgcn_mfma_f32_16x16x32_bf16(
                        af[ot], bf.s8, acc[ot][wt], 0, 0, 0);
            }
        }
    };

    // prologue: row 0 staged
    gload(0); lwrite(0);
    __syncthreads();
    // phase 0: prefetch row 1 under compute of row 0
    gload(1);
    compute(0);
    lwrite(1);
    __syncthreads();
    // phase 1: prefetch row 2 under compute of row 1
    gload(2);
    compute(1);
    lwrite(0);
    __syncthreads();
    // phase 2: compute row 2
    compute(0);

    // write split-K partials (fp16, [kc][b][o][w], w lane-consecutive -> coalesced)
    __half* dst = (__half*)(ws + WS_P) + (size_t)(kc * BB + b) * LL * HH;
#pragma unroll
    for (int ot = 0; ot < 6; ++ot)
#pragma unroll
        for (int wt = 0; wt < 2; ++wt)
#pragma unroll
            for (int r = 0; r < 4; ++r) {
                const int o = ot * 16 + hi * 4 + r;     // C/D: row=(lane>>4)*4+reg
                const int w = wg * 32 + wt * 16 + lo;   //      col=lane&15
                dst[o * HH + w] = __float2half(acc[ot][wt][r]);
            }
}

// ---------------- R: sum partials + bias/dec/cvg -> tanh -> dot v -> scores ----------------
__global__ __launch_bounds__(128) void reduce_kernel(
        const float* __restrict__ attn_b,
        const float* __restrict__ vvec,
        float* __restrict__ ws) {
    const int o = blockIdx.x;   // 0..95
    const int b = blockIdx.y;   // 0..15
    const int h = threadIdx.x;  // 0..127
    const __half* p = (const __half*)(ws + WS_P) + ((size_t)b * LL + o) * HH + h;
    float sum = 0.f;
#pragma unroll
    for (int kc = 0; kc < 32; ++kc)
        sum += __half2float(p[(size_t)kc * BB * LL * HH]);
    float ef = sum + attn_b[o] + ws[WS_DEC + b * HH + h] + ws[WS_CVG + b * LL + o];
    float s = tanhf(ef) * vvec[b * HH + h];
#pragma unroll
    for (int off = 32; off > 0; off >>= 1) s += __shfl_down(s, off, 64);
    __shared__ float r2[2];
    if ((h & 63) == 0) r2[h >> 6] = s;
    __syncthreads();
    if (h == 0) ws[WS_SC + b * LL + o] = r2[0] + r2[1];
}

// ---------------- F: softmax + outputs ----------------
__global__ void finalize_kernel(const float* __restrict__ ws_scores,
                                const float* __restrict__ coverage,
                                const float* __restrict__ enc,
                                float* __restrict__ out) {
    int b = blockIdx.x;
    int t = threadIdx.x;  // 0..127
    __shared__ float sc[LL];
    __shared__ float at[LL];
    if (t < LL) sc[t] = ws_scores[b * LL + t];
    __syncthreads();

    float mx = -1e30f;
    for (int l = 0; l < LL; ++l) mx = fmaxf(mx, sc[l]);
    float sum = 0.f;
    for (int l = 0; l < LL; ++l) sum += expf(sc[l] - mx);

    if (t < LL) {
        float a = expf(sc[t] - mx) / sum;
        at[t] = a;
        out[BB * HH + b * LL + t] = a;                                   // attn
        out[BB * HH + BB * LL + b * LL + t] = coverage[b * LL + t] + a;  // new_coverage
    }
    __syncthreads();

    float ctx = 0.f;
#pragma unroll 8
    for (int l = 0; l < LL; ++l) ctx += at[l] * enc[((size_t)b * LL + l) * HH + t];
    out[b * HH + t] = ctx;                                               // context
}

extern "C" void kernel_launch(void* const* d_in, const int* in_sizes, int n_in,
                              void* d_out, int out_size, void* d_ws, size_t ws_size,
                              hipStream_t stream) {
    const float* hidden   = (const float*)d_in[0];
    const float* enc      = (const float*)d_in[1];
    const float* coverage = (const float*)d_in[2];
    const float* attn_w   = (const float*)d_in[3];
    const float* attn_b   = (const float*)d_in[4];
    const float* cvg_w    = (const float*)d_in[5];
    const float* cvg_b    = (const float*)d_in[6];
    const float* dec_w    = (const float*)d_in[7];
    const float* dec_b    = (const float*)d_in[8];
    const float* vvec     = (const float*)d_in[9];
    float* out = (float*)d_out;
    float* ws = (float*)d_ws;

    prep_kernel<<<128, 256, 0, stream>>>(hidden, enc, coverage, attn_w,
                                         cvg_w, cvg_b, dec_w, dec_b, ws);
    mfma_kernel<<<dim3(32, BB), 256, 0, stream>>>(ws);
    reduce_kernel<<<dim3(LL, BB), 128, 0, stream>>>(attn_b, vvec, ws);
    finalize_kernel<<<BB, HH, 0, stream>>>(ws + WS_SC, coverage, enc, out);
}

// Round 14
// 40.528 us; speedup vs baseline: 2.8161x; 1.0404x over previous
//
#include <hip/hip_runtime.h>
#include <hip/hip_bf16.h>
#include <hip/hip_fp16.h>
#include <math.h>

// Problem constants: B=16, L=96, H=128.
#define BB 16
#define LL 96
#define HH 128
#define NKC 16   // split-K factor (was 32): 6 i-rows per block, K=768

typedef __attribute__((ext_vector_type(8))) short short8;
typedef __attribute__((ext_vector_type(4))) float f32x4;

// Only slice kh=63 of attn_conv_w matters (input height 1, SAME pad (63,64)).
// Only slice kw=63 of cvg_conv_w matters (input width 1, SAME pad (63,64)).
//
// ws layout (float units) — round-8 layout; WS_P now 16 k-chunks of fp16:
#define WS_W    0              // bf16 W [i][o][e ^ ((o&7)<<3)], 1179648 shorts
#define WS_E    589824         // 16*96*256 fp32 zero-padded enc rows [b][i][256]
#define WS_DEC  983040         // 16*128
#define WS_CVG  985088         // 16*96
#define WS_SC   986624         // 16*96
#define WS_P    988160         // fp16 partials [kc][b][o][w]: 16*16*96*128 halves

// ---------------- P1: convert W->bf16 (swizzled), build padded enc, dec_f, cvg_f ----------------
__global__ __launch_bounds__(256) void prep_kernel(
        const float* __restrict__ hidden,
        const float* __restrict__ enc,
        const float* __restrict__ coverage,
        const float* __restrict__ attn_w,
        const float* __restrict__ cvg_w,
        const float* __restrict__ cvg_b,
        const float* __restrict__ dec_w,
        const float* __restrict__ dec_b,
        float* __restrict__ ws) {
    const int bid = blockIdx.x;
    const int tid = threadIdx.x;
    if (bid < 96) {
        // W slice: ws_W[i][o][e] = bf16(attn_w[o][i][63][ e ^ ((o&7)<<3) ])
        const int i = bid;
        unsigned short* wout = (unsigned short*)(ws + WS_W);
        for (int idx = tid; idx < LL * HH; idx += 256) {
            const int o = idx >> 7, e = idx & 127;
            const int esrc = e ^ ((o & 7) << 3);
            float v = attn_w[(((size_t)o * LL + i) * HH + 63) * HH + esrc];
            __hip_bfloat16 h = __float2bfloat16(v);
            wout[(size_t)i * LL * HH + idx] = *(unsigned short*)&h;
        }
    } else if (bid < 112) {
        // padded enc rows: ws_E[b][i][t] = enc[b][i][t-63] for t in [63,191), else 0
        const int b = bid - 96;
        float* eout = ws + WS_E + (size_t)b * LL * 256;
        for (int idx = tid; idx < LL * 256; idx += 256) {
            const int i = idx >> 8, t = idx & 255;
            eout[idx] = (t >= 63 && t < 191) ? enc[((size_t)b * LL + i) * HH + (t - 63)] : 0.f;
        }
    } else {
        const int b = bid - 112;
        __shared__ float hid[HH];
        __shared__ float cov[LL];
        if (tid < HH) hid[tid] = hidden[b * HH + tid];
        if (tid < LL) cov[tid] = coverage[b * LL + tid];
        __syncthreads();
        if (tid < HH) {
            float acc = dec_b[tid];
            for (int k = 0; k < HH; ++k) acc += hid[k] * dec_w[tid * HH + k];
            ws[WS_DEC + b * HH + tid] = acc;
        } else if (tid < HH + LL) {
            const int t = tid - HH;
            float a2 = cvg_b[t];
            for (int i2 = 0; i2 < LL; ++i2)
                a2 += cov[i2] * cvg_w[((size_t)t * LL + i2) * HH + 63];
            ws[WS_CVG + b * LL + t] = a2;
        }
    }
}

// ---------------- M: T14 dbuf (round-13, validated); 6 i-rows per block, K=768 -------------
// grid (kc=16, b=16) = 256 blocks (1/CU); 256 threads = 4 w-split waves.
__global__ __launch_bounds__(256) void mfma_kernel(float* __restrict__ ws) {
    const int kc = blockIdx.x;   // 0..15
    const int b  = blockIdx.y;   // 0..15
    const int tid  = threadIdx.x;
    const int lane = tid & 63;
    const int wg   = tid >> 6;   // wave id 0..3
    const int lo   = lane & 15;
    const int hi   = lane >> 4;  // 0..3

    __shared__ __align__(16) short Abuf[2][LL * HH];  // 2 x 24KB, bf16 W[o][e^]
    __shared__ __align__(16) float Ebuf[2][256];      // 2 x padded enc row (fp32)

    f32x4 acc[6][2];
#pragma unroll
    for (int a = 0; a < 6; ++a)
#pragma unroll
        for (int c = 0; c < 2; ++c) acc[a][c] = f32x4{0.f, 0.f, 0.f, 0.f};

    const short* wsrc = (const short*)(ws + WS_W);
    const float* esrc = ws + WS_E + (size_t)b * LL * 256;

    short8 sA[6];
    float4 sE;

    auto gload = [&](int r) {                 // global -> regs (issue early)
        const short8* s8 = (const short8*)(wsrc + (size_t)(kc * 6 + r) * LL * HH);
#pragma unroll
        for (int t = 0; t < 6; ++t) sA[t] = s8[tid + t * 256];
        if (tid < 64) sE = ((const float4*)(esrc + (kc * 6 + r) * 256))[tid];
    };
    auto lwrite = [&](int buf) {              // regs -> LDS (write late)
        short8* d8 = (short8*)Abuf[buf];
#pragma unroll
        for (int t = 0; t < 6; ++t) d8[tid + t * 256] = sA[t];
        if (tid < 64) ((float4*)Ebuf[buf])[tid] = sE;
    };
    auto compute = [&](int buf) {             // round-8 body verbatim, on buffer `buf`
#pragma unroll
        for (int s = 0; s < 4; ++s) {
            short8 af[6];
#pragma unroll
            for (int ot = 0; ot < 6; ++ot) {
                const int o = ot * 16 + lo;
                const int idx8 = o * 16 + (((s << 2) + hi) ^ (o & 7));
                af[ot] = ((const short8*)Abuf[buf])[idx8];
            }
#pragma unroll
            for (int wt = 0; wt < 2; ++wt) {
                const int t0 = s * 32 + hi * 8 + wg * 32 + wt * 16 + lo;  // <= 247
                union { short8 s8; __hip_bfloat16 h[8]; } bf;
#pragma unroll
                for (int j = 0; j < 8; ++j) bf.h[j] = __float2bfloat16(Ebuf[buf][t0 + j]);
#pragma unroll
                for (int ot = 0; ot < 6; ++ot)
                    acc[ot][wt] = __builtin_amdgcn_mfma_f32_16x16x32_bf16(
                        af[ot], bf.s8, acc[ot][wt], 0, 0, 0);
            }
        }
    };

    // T14 pipeline over 6 rows, fully unrolled (static buffer indices)
    gload(0); lwrite(0);
    __syncthreads();
#pragma unroll
    for (int ii = 0; ii < 6; ++ii) {
        if (ii < 5) gload(ii + 1);
        compute(ii & 1);
        if (ii < 5) {
            lwrite((ii + 1) & 1);
            __syncthreads();
        }
    }

    // write split-K partials (fp16, [kc][b][o][w], w lane-consecutive -> coalesced)
    __half* dst = (__half*)(ws + WS_P) + (size_t)(kc * BB + b) * LL * HH;
#pragma unroll
    for (int ot = 0; ot < 6; ++ot)
#pragma unroll
        for (int wt = 0; wt < 2; ++wt)
#pragma unroll
            for (int r = 0; r < 4; ++r) {
                const int o = ot * 16 + hi * 4 + r;     // C/D: row=(lane>>4)*4+reg
                const int w = wg * 32 + wt * 16 + lo;   //      col=lane&15
                dst[o * HH + w] = __float2half(acc[ot][wt][r]);
            }
}

// ---------------- R: sum partials + bias/dec/cvg -> tanh -> dot v -> scores ----------------
__global__ __launch_bounds__(128) void reduce_kernel(
        const float* __restrict__ attn_b,
        const float* __restrict__ vvec,
        float* __restrict__ ws) {
    const int o = blockIdx.x;   // 0..95
    const int b = blockIdx.y;   // 0..15
    const int h = threadIdx.x;  // 0..127
    const __half* p = (const __half*)(ws + WS_P) + ((size_t)b * LL + o) * HH + h;
    float sum = 0.f;
#pragma unroll
    for (int kc = 0; kc < NKC; ++kc)
        sum += __half2float(p[(size_t)kc * BB * LL * HH]);
    float ef = sum + attn_b[o] + ws[WS_DEC + b * HH + h] + ws[WS_CVG + b * LL + o];
    float s = tanhf(ef) * vvec[b * HH + h];
#pragma unroll
    for (int off = 32; off > 0; off >>= 1) s += __shfl_down(s, off, 64);
    __shared__ float r2[2];
    if ((h & 63) == 0) r2[h >> 6] = s;
    __syncthreads();
    if (h == 0) ws[WS_SC + b * LL + o] = r2[0] + r2[1];
}

// ---------------- F: softmax + outputs ----------------
__global__ void finalize_kernel(const float* __restrict__ ws_scores,
                                const float* __restrict__ coverage,
                                const float* __restrict__ enc,
                                float* __restrict__ out) {
    int b = blockIdx.x;
    int t = threadIdx.x;  // 0..127
    __shared__ float sc[LL];
    __shared__ float at[LL];
    if (t < LL) sc[t] = ws_scores[b * LL + t];
    __syncthreads();

    float mx = -1e30f;
    for (int l = 0; l < LL; ++l) mx = fmaxf(mx, sc[l]);
    float sum = 0.f;
    for (int l = 0; l < LL; ++l) sum += expf(sc[l] - mx);

    if (t < LL) {
        float a = expf(sc[t] - mx) / sum;
        at[t] = a;
        out[BB * HH + b * LL + t] = a;                                   // attn
        out[BB * HH + BB * LL + b * LL + t] = coverage[b * LL + t] + a;  // new_coverage
    }
    __syncthreads();

    float ctx = 0.f;
#pragma unroll 8
    for (int l = 0; l < LL; ++l) ctx += at[l] * enc[((size_t)b * LL + l) * HH + t];
    out[b * HH + t] = ctx;                                               // context
}

extern "C" void kernel_launch(void* const* d_in, const int* in_sizes, int n_in,
                              void* d_out, int out_size, void* d_ws, size_t ws_size,
                              hipStream_t stream) {
    const float* hidden   = (const float*)d_in[0];
    const float* enc      = (const float*)d_in[1];
    const float* coverage = (const float*)d_in[2];
    const float* attn_w   = (const float*)d_in[3];
    const float* attn_b   = (const float*)d_in[4];
    const float* cvg_w    = (const float*)d_in[5];
    const float* cvg_b    = (const float*)d_in[6];
    const float* dec_w    = (const float*)d_in[7];
    const float* dec_b    = (const float*)d_in[8];
    const float* vvec     = (const float*)d_in[9];
    float* out = (float*)d_out;
    float* ws = (float*)d_ws;

    prep_kernel<<<128, 256, 0, stream>>>(hidden, enc, coverage, attn_w,
                                         cvg_w, cvg_b, dec_w, dec_b, ws);
    mfma_kernel<<<dim3(NKC, BB), 256, 0, stream>>>(ws);
    reduce_kernel<<<dim3(LL, BB), 128, 0, stream>>>(attn_b, vvec, ws);
    finalize_kernel<<<BB, HH, 0, stream>>>(ws + WS_SC, coverage, enc, out);
}